// Round 1
// baseline (1473.322 us; speedup 1.0000x reference)
//
#include <hip/hip_runtime.h>
#include <cstdint>
#include <cstddef>

// ---------- types / helpers ----------
using f32x4 = __attribute__((ext_vector_type(4))) float;
using bf16x8 = __attribute__((ext_vector_type(8))) __bf16;
using u16x4 = __attribute__((ext_vector_type(4))) unsigned short;
using u16x8 = __attribute__((ext_vector_type(8))) unsigned short;

#define DEV __device__ __forceinline__

DEV unsigned short f2b(float f) {
  uint32_t u = __builtin_bit_cast(uint32_t, f);
  u += 0x7FFFu + ((u >> 16) & 1u);
  return (unsigned short)(u >> 16);
}

// Problem constants
// B=8, C=256, H=W=128, HEADS=8, hd=32, WS=8, SHIFT=4, nW=256, tokens=131072

// ---------- weight cast fp32 -> bf16 ----------
__global__ void swin_cvt(const float* __restrict__ src, unsigned short* __restrict__ dst, int n) {
  int i = blockIdx.x * 256 + threadIdx.x;
  if (i < n) dst[i] = f2b(src[i]);
}

// ---------- LN1 stats over channel dim, reading x in (B,C,H,W) coalesced ----------
__global__ void swin_ln1_stats(const float* __restrict__ x, float* __restrict__ st) {
  __shared__ float sh[512];
  int bh = blockIdx.x;          // b*128 + h
  int t = threadIdx.x;
  int w = t & 127, ch = t >> 7; // channel-half
  const float* px = x + (((size_t)(bh >> 7) * 256 + ch * 128) << 14) + ((size_t)(bh & 127) << 7) + w;
  float s = 0.f, s2 = 0.f;
  for (int c = 0; c < 128; ++c) {
    float v = px[(size_t)c << 14];
    s += v; s2 += v * v;
  }
  sh[t] = s; sh[256 + t] = s2;
  __syncthreads();
  if (ch == 0) {
    s += sh[t + 128]; s2 += sh[256 + t + 128];
    float mean = s * (1.f / 256.f);
    float var = s2 * (1.f / 256.f) - mean * mean;
    int tok = (bh << 7) + w;
    st[(size_t)tok * 2] = mean;
    st[(size_t)tok * 2 + 1] = rsqrtf(var + 1e-5f);
  }
}

// ---------- normalize + cyclic shift + window partition -> win bf16 (2048,64,256) ----------
__global__ void swin_win_pass(const float* __restrict__ x, const float* __restrict__ st,
                              const float* __restrict__ lw, const float* __restrict__ lb,
                              unsigned short* __restrict__ win) {
  __shared__ float tile[64 * 129];
  int bid = blockIdx.x;
  int ct = bid & 3; int bh = bid >> 2;
  int b = bh >> 7, h = bh & 127;
  int c0 = ct << 6;
  int t = threadIdx.x;
#pragma unroll
  for (int i = 0; i < 32; ++i) {
    int id = (i << 8) + t;
    int cl_ = id >> 7, w = id & 127;
    tile[cl_ * 129 + w] = x[(((size_t)(b * 256 + c0 + cl_)) << 14) + (h << 7) + w];
  }
  __syncthreads();
  int hp = (h + 124) & 127;           // shifted row coord
  int whh = hp >> 3, nh = hp & 7;
#pragma unroll
  for (int i = 0; i < 32; ++i) {
    int id = (i << 8) + t;
    int w = id >> 6, cc = id & 63;
    float mean = st[(((size_t)bh << 7) + w) * 2];
    float rstd = st[(((size_t)bh << 7) + w) * 2 + 1];
    float v = tile[cc * 129 + w];
    v = (v - mean) * rstd * lw[c0 + cc] + lb[c0 + cc];
    int wp_ = (w + 124) & 127;        // shifted col coord
    int wwc = wp_ >> 3, nw = wp_ & 7;
    size_t wt = (size_t)b * 256 + whh * 16 + wwc;
    int n = (nh << 3) + nw;
    win[((wt << 6) + n) * 256 + c0 + cc] = f2b(v);
  }
}

// ---------- generic bf16 GEMM: C = A(M,K) @ W(N,K)^T, templated epilogue ----------
// MODE 0: QKV  -> bf16 out (ld 768), bias, scale q-part
// MODE 1: PROJ -> fp32 T, bias + shortcut x with window-reverse+unshift
// MODE 2: FC1  -> bf16 h2 (ld 1024), bias + gelu(tanh approx)
// MODE 3: FC2  -> fp32 d_out (B,C,H,W), bias + T residual, transpose-store
template<int MODE>
__global__ __launch_bounds__(256)
void swin_gemm(const unsigned short* __restrict__ A,
               const unsigned short* __restrict__ Wt,
               const float* __restrict__ bias,
               void* __restrict__ outp,
               const float* __restrict__ extra,
               int M, int N, int K) {
  constexpr int LDS_S = 56;  // 32 cols + pad; 112B rows: 16B aligned, ~2-way banks
  __shared__ unsigned short As[128 * LDS_S];
  __shared__ unsigned short Bs[128 * LDS_S];
  const int nbn = N >> 7;
  const int bm = blockIdx.x / nbn;
  const int bn = blockIdx.x % nbn;
  const int m0 = bm << 7, n0 = bn << 7;
  const int t = threadIdx.x;
  const int lane = t & 63;
  const int wave = t >> 6;
  const int wr = wave >> 1, wc = wave & 1;
  const int cl = lane & 15, g = lane >> 4;
  const int cc = (t & 3) << 3;  // k-chunk within row
  const int KT = K >> 5;

  auto gaddr = [&](const unsigned short* base, int tile0, int kt, int c) {
    int row = (c << 6) + (t >> 2);
    return (const uint4*)(base + (size_t)(tile0 + row) * K + (kt << 5) + cc);
  };

  uint4 ra[2], rb[2];
  ra[0] = *gaddr(A, m0, 0, 0);  ra[1] = *gaddr(A, m0, 0, 1);
  rb[0] = *gaddr(Wt, n0, 0, 0); rb[1] = *gaddr(Wt, n0, 0, 1);

  f32x4 acc[4][4] = {};

  for (int kt = 0; kt < KT; ++kt) {
    __syncthreads();
#pragma unroll
    for (int c = 0; c < 2; ++c) {
      int row = (c << 6) + (t >> 2);
      *(uint4*)&As[row * LDS_S + cc] = ra[c];
      *(uint4*)&Bs[row * LDS_S + cc] = rb[c];
    }
    __syncthreads();
    if (kt + 1 < KT) {
      ra[0] = *gaddr(A, m0, kt + 1, 0);  ra[1] = *gaddr(A, m0, kt + 1, 1);
      rb[0] = *gaddr(Wt, n0, kt + 1, 0); rb[1] = *gaddr(Wt, n0, kt + 1, 1);
    }
    bf16x8 af[4], bfr[4];
#pragma unroll
    for (int i = 0; i < 4; ++i) {
      af[i]  = *(const bf16x8*)&As[(wr * 64 + i * 16 + cl) * LDS_S + g * 8];
      bfr[i] = *(const bf16x8*)&Bs[(wc * 64 + i * 16 + cl) * LDS_S + g * 8];
    }
#pragma unroll
    for (int i = 0; i < 4; ++i)
#pragma unroll
      for (int j = 0; j < 4; ++j)
        acc[i][j] = __builtin_amdgcn_mfma_f32_16x16x32_bf16(af[i], bfr[j], acc[i][j], 0, 0, 0);
  }

  if constexpr (MODE == 3) {
#pragma unroll
    for (int i = 0; i < 4; ++i) {
      int rowb = m0 + wr * 64 + i * 16 + (g << 2);
      int b = rowb >> 14, hw = rowb & 16383;
#pragma unroll
      for (int j = 0; j < 4; ++j) {
        int col = n0 + wc * 64 + j * 16 + cl;
        float bs = bias[col];
        f32x4 vv;
#pragma unroll
        for (int r = 0; r < 4; ++r)
          vv[r] = acc[i][j][r] + bs + extra[((size_t)(rowb + r) << 8) + col];
        *(f32x4*)&((float*)outp)[(((size_t)(b << 8) + col) << 14) + hw] = vv;
      }
    }
  } else {
#pragma unroll
    for (int i = 0; i < 4; ++i)
#pragma unroll
      for (int j = 0; j < 4; ++j)
#pragma unroll
        for (int r = 0; r < 4; ++r) {
          int row = m0 + wr * 64 + i * 16 + (g << 2) + r;
          int col = n0 + wc * 64 + j * 16 + cl;
          float v = acc[i][j][r];
          if constexpr (MODE == 0) {
            v += bias[col];
            if (col < 256) v *= 0.17677669529663687f;  // 1/sqrt(32), matches (qkv+b)*scale
            ((unsigned short*)outp)[(size_t)row * 768 + col] = f2b(v);
          } else if constexpr (MODE == 1) {
            v += bias[col];
            int wdw = row >> 6, n = row & 63;
            int b = wdw >> 8, wi = wdw & 255;
            int hs = ((wi >> 4) << 3) + (n >> 3);
            int ws2 = ((wi & 15) << 3) + (n & 7);
            int hh = (hs + 4) & 127, ww2 = (ws2 + 4) & 127;
            int hw = (hh << 7) + ww2;
            float sc = extra[(((size_t)(b * 256 + col)) << 14) + hw];  // x shortcut (NCHW)
            ((float*)outp)[(((size_t)(b << 14) + hw) << 8) + col] = v + sc;
          } else {  // MODE 2: FC1 + gelu(tanh)
            v += bias[col];
            float u = 0.7978845608028654f * (v + 0.044715f * v * v * v);
            float e = __expf(2.f * u);
            float th = 1.f - 2.f / (e + 1.f);
            ((unsigned short*)outp)[(size_t)row * 1024 + col] = f2b(0.5f * v * (1.f + th));
          }
        }
  }
}

// ---------- windowed attention: one block = (window, 4 heads), 1 wave/head ----------
__global__ __launch_bounds__(256)
void swin_attn(const unsigned short* __restrict__ qkv,
               const float* __restrict__ relb,
               unsigned short* __restrict__ attn_out) {
  __shared__ unsigned short Plds[4][64 * 68];
  __shared__ unsigned short Vlds[4][32 * 68];
  int bid = blockIdx.x;
  int w = bid >> 1, hg = bid & 1;
  int t = threadIdx.x;
  int wave = t >> 6, lane = t & 63;
  int head = (hg << 2) + wave;
  int cl = lane & 15, g = lane >> 4;
  const size_t wb = (size_t)w * 64 * 768;

  // Q,K fragments straight from global (row-major (n,32) per head)
  bf16x8 qf[4], kf[4];
#pragma unroll
  for (int ni = 0; ni < 4; ++ni) {
    int n = (ni << 4) + cl;
    qf[ni] = *(const bf16x8*)(qkv + wb + (size_t)n * 768 + (head << 5) + (g << 3));
    kf[ni] = *(const bf16x8*)(qkv + wb + (size_t)n * 768 + 256 + (head << 5) + (g << 3));
  }

  // S^T[m][n] = k_m . q_n  (q pre-scaled in QKV epilogue)
  f32x4 s[4][4] = {};
#pragma unroll
  for (int mi = 0; mi < 4; ++mi)
#pragma unroll
    for (int ni = 0; ni < 4; ++ni)
      s[mi][ni] = __builtin_amdgcn_mfma_f32_16x16x32_bf16(kf[mi], qf[ni], s[mi][ni], 0, 0, 0);

  // stage V transposed into LDS: Vlds[d][m]
#pragma unroll
  for (int c = 0; c < 4; ++c) {
    int id = (c << 6) + lane;
    int m = id >> 2, dc = (id & 3) << 3;
    u16x8 vv = *(const u16x8*)(qkv + wb + (size_t)m * 768 + 512 + (head << 5) + dc);
#pragma unroll
    for (int j = 0; j < 8; ++j)
      Vlds[wave][(dc + j) * 68 + m] = vv[j];
  }

  // bias + shifted-window mask + softmax over m (lane-local 16 + 2 shuffles)
  int wi = w & 255;
  bool eh = (wi >> 4) == 15, ew = (wi & 15) == 15;
#pragma unroll
  for (int ni = 0; ni < 4; ++ni) {
    int n = (ni << 4) + cl;
    int nh = n >> 3, nw = n & 7;
    int rn = (eh ? ((nh >> 2) + 1) : 0) * 3 + (ew ? ((nw >> 2) + 1) : 0);
    float mx = -1e30f;
#pragma unroll
    for (int mi = 0; mi < 4; ++mi)
#pragma unroll
      for (int r = 0; r < 4; ++r) {
        int m = (mi << 4) + (g << 2) + r;
        int mh = m >> 3, mw = m & 7;
        int rm = (eh ? ((mh >> 2) + 1) : 0) * 3 + (ew ? ((mw >> 2) + 1) : 0);
        float v = s[mi][ni][r] + relb[(size_t)((nh - mh + 7) * 15 + (nw - mw + 7)) * 8 + head];
        if (rn != rm) v -= 100.f;
        s[mi][ni][r] = v;
        mx = fmaxf(mx, v);
      }
    mx = fmaxf(mx, __shfl_xor(mx, 16));
    mx = fmaxf(mx, __shfl_xor(mx, 32));
    float sum = 0.f;
#pragma unroll
    for (int mi = 0; mi < 4; ++mi)
#pragma unroll
      for (int r = 0; r < 4; ++r) {
        float p = __expf(s[mi][ni][r] - mx);
        s[mi][ni][r] = p;
        sum += p;
      }
    sum += __shfl_xor(sum, 16);
    sum += __shfl_xor(sum, 32);
    float inv = 1.f / sum;
#pragma unroll
    for (int mi = 0; mi < 4; ++mi) {
      u16x4 pk;
#pragma unroll
      for (int r = 0; r < 4; ++r) pk[r] = f2b(s[mi][ni][r] * inv);
      *(u16x4*)&Plds[wave][n * 68 + (mi << 4) + (g << 2)] = pk;
    }
  }
  __syncthreads();

  union FragU { bf16x8 v; uint64_t q[2]; };
  f32x4 o[4][2] = {};
#pragma unroll
  for (int mt = 0; mt < 2; ++mt) {
    FragU vf[2];
#pragma unroll
    for (int dt = 0; dt < 2; ++dt) {
      int d = (dt << 4) + cl;
      const unsigned short* p = &Vlds[wave][d * 68 + (mt << 5) + (g << 3)];
      vf[dt].q[0] = *(const uint64_t*)p;
      vf[dt].q[1] = *(const uint64_t*)(p + 4);
    }
#pragma unroll
    for (int ni = 0; ni < 4; ++ni) {
      FragU pa;
      const unsigned short* pp = &Plds[wave][((ni << 4) + cl) * 68 + (mt << 5) + (g << 3)];
      pa.q[0] = *(const uint64_t*)pp;
      pa.q[1] = *(const uint64_t*)(pp + 4);
#pragma unroll
      for (int dt = 0; dt < 2; ++dt)
        o[ni][dt] = __builtin_amdgcn_mfma_f32_16x16x32_bf16(pa.v, vf[dt].v, o[ni][dt], 0, 0, 0);
    }
  }

#pragma unroll
  for (int ni = 0; ni < 4; ++ni)
#pragma unroll
    for (int dt = 0; dt < 2; ++dt)
#pragma unroll
      for (int r = 0; r < 4; ++r) {
        int n = (ni << 4) + (g << 2) + r;
        int d = (dt << 4) + cl;
        attn_out[((size_t)w * 64 + n) * 256 + (head << 5) + d] = f2b(o[ni][dt][r]);
      }
}

// ---------- LN2 stats (wave per token) ----------
__global__ void swin_ln2_stats(const float* __restrict__ T, float* __restrict__ st) {
  int tok = (blockIdx.x << 2) + (threadIdx.x >> 6);
  int lane = threadIdx.x & 63;
  f32x4 v = *(const f32x4*)(T + ((size_t)tok << 8) + (lane << 2));
  float s = v[0] + v[1] + v[2] + v[3];
  float s2 = v[0] * v[0] + v[1] * v[1] + v[2] * v[2] + v[3] * v[3];
#pragma unroll
  for (int off = 32; off > 0; off >>= 1) {
    s += __shfl_xor(s, off);
    s2 += __shfl_xor(s2, off);
  }
  if (lane == 0) {
    float mean = s * (1.f / 256.f);
    float var = s2 * (1.f / 256.f) - mean * mean;
    st[(size_t)tok * 2] = mean;
    st[(size_t)tok * 2 + 1] = rsqrtf(var + 1e-5f);
  }
}

// ---------- LN2 normalize -> bf16 ----------
__global__ void swin_tn_pass(const float* __restrict__ T, const float* __restrict__ st,
                             const float* __restrict__ lw, const float* __restrict__ lb,
                             unsigned short* __restrict__ tn) {
  size_t idx = ((size_t)blockIdx.x << 8) + threadIdx.x;  // one float4 each
  int tok = (int)(idx >> 6);
  int c4 = (int)(idx & 63) << 2;
  f32x4 v = *(const f32x4*)(T + ((size_t)tok << 8) + c4);
  float mean = st[(size_t)tok * 2], rstd = st[(size_t)tok * 2 + 1];
  f32x4 wv = *(const f32x4*)(lw + c4);
  f32x4 bv = *(const f32x4*)(lb + c4);
  u16x4 o;
#pragma unroll
  for (int j = 0; j < 4; ++j) o[j] = f2b((v[j] - mean) * rstd * wv[j] + bv[j]);
  *(u16x4*)(tn + (idx << 2)) = o;
}

// ---------- launch ----------
extern "C" void kernel_launch(void* const* d_in, const int* in_sizes, int n_in,
                              void* d_out, int out_size, void* d_ws, size_t ws_size,
                              hipStream_t stream) {
  const float* x    = (const float*)d_in[0];
  const float* ln1w = (const float*)d_in[1];
  const float* ln1b = (const float*)d_in[2];
  const float* qkvw = (const float*)d_in[3];
  const float* qkvb = (const float*)d_in[4];
  const float* relb = (const float*)d_in[5];
  const float* projw = (const float*)d_in[6];
  const float* projb = (const float*)d_in[7];
  const float* ln2w = (const float*)d_in[8];
  const float* ln2b = (const float*)d_in[9];
  const float* fc1w = (const float*)d_in[10];
  const float* fc1b = (const float*)d_in[11];
  const float* fc2w = (const float*)d_in[12];
  const float* fc2b = (const float*)d_in[13];

  char* ws = (char*)d_ws;
  unsigned short* win = (unsigned short*)(ws);                  // 67,108,864 B
  unsigned short* qkv = (unsigned short*)(ws + 67108864);       // 201,326,592 B
  float* T            = (float*)(ws + 268435456);               // 134,217,728 B
  float* stats1       = (float*)(ws + 402653184);               // 1,048,576 B
  float* stats2       = (float*)(ws + 403701760);               // 1,048,576 B
  unsigned short* wq  = (unsigned short*)(ws + 404750336);      // 393,216 B
  unsigned short* wp  = (unsigned short*)(ws + 405143552);      // 131,072 B
  unsigned short* w1  = (unsigned short*)(ws + 405274624);      // 524,288 B
  unsigned short* w2  = (unsigned short*)(ws + 405798912);      // 524,288 B -> end 406,323,200
  unsigned short* attn_out = win;                // reuse (win dead after QKV)
  unsigned short* h2  = (unsigned short*)(ws);   // 268,435,456 B (win+qkv regions, dead)
  unsigned short* tn  = (unsigned short*)d_out;  // 67 MB scratch inside d_out (overwritten by FC2)

  if (ws_size < 406323200ull) return;  // workspace too small: fail loudly (poison stays)

  swin_cvt<<<(196608 + 255) / 256, 256, 0, stream>>>(qkvw, wq, 196608);
  swin_cvt<<<(65536 + 255) / 256, 256, 0, stream>>>(projw, wp, 65536);
  swin_cvt<<<(262144 + 255) / 256, 256, 0, stream>>>(fc1w, w1, 262144);
  swin_cvt<<<(262144 + 255) / 256, 256, 0, stream>>>(fc2w, w2, 262144);

  swin_ln1_stats<<<1024, 256, 0, stream>>>(x, stats1);
  swin_win_pass<<<4096, 256, 0, stream>>>(x, stats1, ln1w, ln1b, win);
  swin_gemm<0><<<6144, 256, 0, stream>>>(win, wq, qkvb, qkv, nullptr, 131072, 768, 256);
  swin_attn<<<4096, 256, 0, stream>>>(qkv, relb, attn_out);
  swin_gemm<1><<<2048, 256, 0, stream>>>(attn_out, wp, projb, T, x, 131072, 256, 256);
  swin_ln2_stats<<<32768, 256, 0, stream>>>(T, stats2);
  swin_tn_pass<<<32768, 256, 0, stream>>>(T, stats2, ln2w, ln2b, tn);
  swin_gemm<2><<<8192, 256, 0, stream>>>(tn, w1, fc1b, h2, nullptr, 131072, 1024, 256);
  swin_gemm<3><<<2048, 256, 0, stream>>>(h2, w2, fc2b, d_out, T, 131072, 256, 1024);
}

// Round 2
// 841.557 us; speedup vs baseline: 1.7507x; 1.7507x over previous
//
#include <hip/hip_runtime.h>
#include <cstdint>
#include <cstddef>

// ---------- types / helpers ----------
using f32x4 = __attribute__((ext_vector_type(4))) float;
using bf16x8 = __attribute__((ext_vector_type(8))) __bf16;
using u16x4 = __attribute__((ext_vector_type(4))) unsigned short;
using u16x8 = __attribute__((ext_vector_type(8))) unsigned short;

#define DEV __device__ __forceinline__

DEV unsigned short f2b(float f) {
  uint32_t u = __builtin_bit_cast(uint32_t, f);
  u += 0x7FFFu + ((u >> 16) & 1u);
  return (unsigned short)(u >> 16);
}

// async global->LDS, 16B per lane. LDS dest must be wave-uniform base + lane*16.
DEV void gload16(const unsigned short* g, unsigned short* l) {
  __builtin_amdgcn_global_load_lds(
      (const __attribute__((address_space(1))) void*)g,
      (__attribute__((address_space(3))) void*)l, 16, 0, 0);
}

// Problem constants
// B=8, C=256, H=W=128, HEADS=8, hd=32, WS=8, SHIFT=4, nW=256, tokens=131072

// ---------- weight cast fp32 -> bf16 ----------
__global__ void swin_cvt(const float* __restrict__ src, unsigned short* __restrict__ dst, int n) {
  int i = blockIdx.x * 256 + threadIdx.x;
  if (i < n) dst[i] = f2b(src[i]);
}

// ---------- LN1 stats over channel dim, reading x in (B,C,H,W) coalesced ----------
__global__ void swin_ln1_stats(const float* __restrict__ x, float* __restrict__ st) {
  __shared__ float sh[512];
  int bh = blockIdx.x;          // b*128 + h
  int t = threadIdx.x;
  int w = t & 127, ch = t >> 7; // channel-half
  const float* px = x + (((size_t)(bh >> 7) * 256 + ch * 128) << 14) + ((size_t)(bh & 127) << 7) + w;
  float s = 0.f, s2 = 0.f;
  for (int c = 0; c < 128; ++c) {
    float v = px[(size_t)c << 14];
    s += v; s2 += v * v;
  }
  sh[t] = s; sh[256 + t] = s2;
  __syncthreads();
  if (ch == 0) {
    s += sh[t + 128]; s2 += sh[256 + t + 128];
    float mean = s * (1.f / 256.f);
    float var = s2 * (1.f / 256.f) - mean * mean;
    int tok = (bh << 7) + w;
    st[(size_t)tok * 2] = mean;
    st[(size_t)tok * 2 + 1] = rsqrtf(var + 1e-5f);
  }
}

// ---------- normalize + cyclic shift + window partition -> win bf16 (2048,64,256) ----------
__global__ void swin_win_pass(const float* __restrict__ x, const float* __restrict__ st,
                              const float* __restrict__ lw, const float* __restrict__ lb,
                              unsigned short* __restrict__ win) {
  __shared__ float tile[64 * 129];
  int bid = blockIdx.x;
  int ct = bid & 3; int bh = bid >> 2;
  int b = bh >> 7, h = bh & 127;
  int c0 = ct << 6;
  int t = threadIdx.x;
#pragma unroll
  for (int i = 0; i < 32; ++i) {
    int id = (i << 8) + t;
    int cl_ = id >> 7, w = id & 127;
    tile[cl_ * 129 + w] = x[(((size_t)(b * 256 + c0 + cl_)) << 14) + (h << 7) + w];
  }
  __syncthreads();
  int hp = (h + 124) & 127;           // shifted row coord
  int whh = hp >> 3, nh = hp & 7;
#pragma unroll
  for (int i = 0; i < 32; ++i) {
    int id = (i << 8) + t;
    int w = id >> 6, cc = id & 63;
    float mean = st[(((size_t)bh << 7) + w) * 2];
    float rstd = st[(((size_t)bh << 7) + w) * 2 + 1];
    float v = tile[cc * 129 + w];
    v = (v - mean) * rstd * lw[c0 + cc] + lb[c0 + cc];
    int wp_ = (w + 124) & 127;        // shifted col coord
    int wwc = wp_ >> 3, nw = wp_ & 7;
    size_t wt = (size_t)b * 256 + whh * 16 + wwc;
    int n = (nh << 3) + nw;
    win[((wt << 6) + n) * 256 + c0 + cc] = f2b(v);
  }
}

// ---------- bf16 GEMM: C = A(M,K) @ W(N,K)^T, m97-style global_load_lds staging ----------
// Swizzle: LDS linear [128][32] u16; 16B chunk kc within row holds global chunk kc^(row&3).
// MODE 0: QKV  -> bf16 out (ld 768), bias, scale q-part       [swapped: 4 cols/lane reg]
// MODE 1: PROJ -> fp32 T token-major, bias + x shortcut       [swapped]
// MODE 2: FC1  -> bf16 h2 (ld 1024), bias + gelu              [swapped]
// MODE 3: FC2  -> fp32 d_out NCHW, bias + T residual          [unswapped: 4 rows/lane reg]
template<int MODE>
__global__ __launch_bounds__(256)
void swin_gemm(const unsigned short* __restrict__ A,
               const unsigned short* __restrict__ Wt,
               const float* __restrict__ bias,
               void* __restrict__ outp,
               const float* __restrict__ extra,
               int M, int N, int K) {
  __shared__ unsigned short As[128 * 32];
  __shared__ unsigned short Bs[128 * 32];
  const int nbn = N >> 7;
  const int bm = blockIdx.x / nbn;
  const int bn = blockIdx.x % nbn;
  const int m0 = bm << 7, n0 = bn << 7;
  const int t = threadIdx.x;
  const int lane = t & 63;
  const int wave = t >> 6;
  const int wr = wave >> 1, wc = wave & 1;
  const int cl = lane & 15, g = lane >> 4;
  const int KT = K >> 5;

  // staging addresses: chunk id c*256+t -> row=(cid>>2), kc=cid&3, source kc^=(row&3)
  const int row0 = t >> 2;            // 0..63
  const int ks = (t & 3) ^ (row0 & 3);
  const size_t aoff0 = (size_t)(m0 + row0) * K + ks * 8;
  const size_t aoff1 = (size_t)(m0 + 64 + row0) * K + ks * 8;
  const size_t boff0 = (size_t)(n0 + row0) * K + ks * 8;
  const size_t boff1 = (size_t)(n0 + 64 + row0) * K + ks * 8;
  unsigned short* la0 = As + t * 8;
  unsigned short* la1 = As + 2048 + t * 8;
  unsigned short* lb0 = Bs + t * 8;
  unsigned short* lb1 = Bs + 2048 + t * 8;

  // fragment read offsets (swizzled)
  const int ra_ = wr * 64 + cl;            // + i*16
  const int rb_ = wc * 64 + cl;
  const int ka = (g ^ (cl & 3)) * 8;       // (row&3)==(cl&3) since i*16,wr*64 are mult of 4

  f32x4 acc[4][4] = {};

  for (int kt = 0; kt < KT; ++kt) {
    __syncthreads();
    const size_t ko = (size_t)kt * 32;
    gload16(A + aoff0 + ko, la0);
    gload16(A + aoff1 + ko, la1);
    gload16(Wt + boff0 + ko, lb0);
    gload16(Wt + boff1 + ko, lb1);
    __syncthreads();
    bf16x8 af[4], bfr[4];
#pragma unroll
    for (int i = 0; i < 4; ++i) {
      af[i]  = *(const bf16x8*)&As[(ra_ + i * 16) * 32 + ka];
      bfr[i] = *(const bf16x8*)&Bs[(rb_ + i * 16) * 32 + ka];
    }
#pragma unroll
    for (int i = 0; i < 4; ++i)
#pragma unroll
      for (int j = 0; j < 4; ++j) {
        if constexpr (MODE == 3)
          acc[i][j] = __builtin_amdgcn_mfma_f32_16x16x32_bf16(af[i], bfr[j], acc[i][j], 0, 0, 0);
        else
          acc[i][j] = __builtin_amdgcn_mfma_f32_16x16x32_bf16(bfr[j], af[i], acc[i][j], 0, 0, 0);
      }
  }

  if constexpr (MODE == 3) {
    // lane: cl -> col, regs -> 4 consecutive rows(=hw). f32x4 store along hw (NCHW).
#pragma unroll
    for (int i = 0; i < 4; ++i) {
      int rowb = m0 + wr * 64 + i * 16 + (g << 2);
      int b = rowb >> 14, hw = rowb & 16383;
#pragma unroll
      for (int j = 0; j < 4; ++j) {
        int col = n0 + wc * 64 + j * 16 + cl;
        float bs = bias[col];
        f32x4 vv;
#pragma unroll
        for (int r = 0; r < 4; ++r)
          vv[r] = acc[i][j][r] + bs + extra[((size_t)(rowb + r) << 8) + col];
        *(f32x4*)&((float*)outp)[(((size_t)(b << 8) + col) << 14) + hw] = vv;
      }
    }
  } else {
    // swapped: lane cl -> row, regs -> 4 consecutive cols. vector stores along col.
#pragma unroll
    for (int i = 0; i < 4; ++i) {
      int row = m0 + wr * 64 + i * 16 + cl;
#pragma unroll
      for (int j = 0; j < 4; ++j) {
        int colb = n0 + wc * 64 + j * 16 + (g << 2);
        f32x4 b4 = *(const f32x4*)(bias + colb);
        if constexpr (MODE == 0) {
          const bool qs = (n0 < 256);
          u16x4 o;
#pragma unroll
          for (int r = 0; r < 4; ++r) {
            float v = acc[i][j][r] + b4[r];
            if (qs) v *= 0.17677669529663687f;  // 1/sqrt(32)
            o[r] = f2b(v);
          }
          *(u16x4*)((unsigned short*)outp + (size_t)row * 768 + colb) = o;
        } else if constexpr (MODE == 1) {
          int b = row >> 14, hw = row & 16383;
          f32x4 vv;
#pragma unroll
          for (int r = 0; r < 4; ++r)
            vv[r] = acc[i][j][r] + b4[r] +
                    extra[((size_t)(b * 256 + colb + r) << 14) + hw];
          *(f32x4*)((float*)outp + (size_t)row * 256 + colb) = vv;
        } else {  // MODE 2: FC1 + gelu(tanh)
          u16x4 o;
#pragma unroll
          for (int r = 0; r < 4; ++r) {
            float v = acc[i][j][r] + b4[r];
            float u = 0.7978845608028654f * (v + 0.044715f * v * v * v);
            float e = __expf(2.f * u);
            float th = 1.f - 2.f / (e + 1.f);
            o[r] = f2b(0.5f * v * (1.f + th));
          }
          *(u16x4*)((unsigned short*)outp + (size_t)row * 1024 + colb) = o;
        }
      }
    }
  }
}

// ---------- windowed attention: one block = (window, 4 heads), 1 wave/head ----------
// Output written in TOKEN order (window-reverse + unshift fused into the store).
__global__ __launch_bounds__(256)
void swin_attn(const unsigned short* __restrict__ qkv,
               const float* __restrict__ relb,
               unsigned short* __restrict__ attn_out) {
  __shared__ unsigned short Plds[4][64 * 68];
  __shared__ unsigned short Vlds[4][32 * 68];
  int bid = blockIdx.x;
  int w = bid >> 1, hg = bid & 1;
  int t = threadIdx.x;
  int wave = t >> 6, lane = t & 63;
  int head = (hg << 2) + wave;
  int cl = lane & 15, g = lane >> 4;
  const size_t wb = (size_t)w * 64 * 768;

  bf16x8 qf[4], kf[4];
#pragma unroll
  for (int ni = 0; ni < 4; ++ni) {
    int n = (ni << 4) + cl;
    qf[ni] = *(const bf16x8*)(qkv + wb + (size_t)n * 768 + (head << 5) + (g << 3));
    kf[ni] = *(const bf16x8*)(qkv + wb + (size_t)n * 768 + 256 + (head << 5) + (g << 3));
  }

  f32x4 s[4][4] = {};
#pragma unroll
  for (int mi = 0; mi < 4; ++mi)
#pragma unroll
    for (int ni = 0; ni < 4; ++ni)
      s[mi][ni] = __builtin_amdgcn_mfma_f32_16x16x32_bf16(kf[mi], qf[ni], s[mi][ni], 0, 0, 0);

#pragma unroll
  for (int c = 0; c < 4; ++c) {
    int id = (c << 6) + lane;
    int m = id >> 2, dc = (id & 3) << 3;
    u16x8 vv = *(const u16x8*)(qkv + wb + (size_t)m * 768 + 512 + (head << 5) + dc);
#pragma unroll
    for (int j = 0; j < 8; ++j)
      Vlds[wave][(dc + j) * 68 + m] = vv[j];
  }

  int wi = w & 255;
  bool eh = (wi >> 4) == 15, ew = (wi & 15) == 15;
#pragma unroll
  for (int ni = 0; ni < 4; ++ni) {
    int n = (ni << 4) + cl;
    int nh = n >> 3, nw = n & 7;
    int rn = (eh ? ((nh >> 2) + 1) : 0) * 3 + (ew ? ((nw >> 2) + 1) : 0);
    float mx = -1e30f;
#pragma unroll
    for (int mi = 0; mi < 4; ++mi)
#pragma unroll
      for (int r = 0; r < 4; ++r) {
        int m = (mi << 4) + (g << 2) + r;
        int mh = m >> 3, mw = m & 7;
        int rm = (eh ? ((mh >> 2) + 1) : 0) * 3 + (ew ? ((mw >> 2) + 1) : 0);
        float v = s[mi][ni][r] + relb[(size_t)((nh - mh + 7) * 15 + (nw - mw + 7)) * 8 + head];
        if (rn != rm) v -= 100.f;
        s[mi][ni][r] = v;
        mx = fmaxf(mx, v);
      }
    mx = fmaxf(mx, __shfl_xor(mx, 16));
    mx = fmaxf(mx, __shfl_xor(mx, 32));
    float sum = 0.f;
#pragma unroll
    for (int mi = 0; mi < 4; ++mi)
#pragma unroll
      for (int r = 0; r < 4; ++r) {
        float p = __expf(s[mi][ni][r] - mx);
        s[mi][ni][r] = p;
        sum += p;
      }
    sum += __shfl_xor(sum, 16);
    sum += __shfl_xor(sum, 32);
    float inv = 1.f / sum;
#pragma unroll
    for (int mi = 0; mi < 4; ++mi) {
      u16x4 pk;
#pragma unroll
      for (int r = 0; r < 4; ++r) pk[r] = f2b(s[mi][ni][r] * inv);
      *(u16x4*)&Plds[wave][n * 68 + (mi << 4) + (g << 2)] = pk;
    }
  }
  __syncthreads();

  union FragU { bf16x8 v; uint64_t q[2]; };
  f32x4 o[4][2] = {};
#pragma unroll
  for (int mt = 0; mt < 2; ++mt) {
    FragU vf[2];
#pragma unroll
    for (int dt = 0; dt < 2; ++dt) {
      int d = (dt << 4) + cl;
      const unsigned short* p = &Vlds[wave][d * 68 + (mt << 5) + (g << 3)];
      vf[dt].q[0] = *(const uint64_t*)p;
      vf[dt].q[1] = *(const uint64_t*)(p + 4);
    }
#pragma unroll
    for (int ni = 0; ni < 4; ++ni) {
      FragU pa;
      const unsigned short* pp = &Plds[wave][((ni << 4) + cl) * 68 + (mt << 5) + (g << 3)];
      pa.q[0] = *(const uint64_t*)pp;
      pa.q[1] = *(const uint64_t*)(pp + 4);
#pragma unroll
      for (int dt = 0; dt < 2; ++dt)
        o[ni][dt] = __builtin_amdgcn_mfma_f32_16x16x32_bf16(pa.v, vf[dt].v, o[ni][dt], 0, 0, 0);
    }
  }

  int b = w >> 8;
#pragma unroll
  for (int ni = 0; ni < 4; ++ni)
#pragma unroll
    for (int dt = 0; dt < 2; ++dt)
#pragma unroll
      for (int r = 0; r < 4; ++r) {
        int n = (ni << 4) + (g << 2) + r;
        int d = (dt << 4) + cl;
        int hs = ((wi >> 4) << 3) + (n >> 3), ws_ = ((wi & 15) << 3) + (n & 7);
        int hh = (hs + 4) & 127, ww = (ws_ + 4) & 127;
        size_t tok = ((size_t)b << 14) + (hh << 7) + ww;
        attn_out[tok * 256 + (head << 5) + d] = f2b(o[ni][dt][r]);
      }
}

// ---------- fused LN2: stats + normalize -> bf16, one read of T ----------
__global__ void swin_ln2_fused(const float* __restrict__ T,
                               const float* __restrict__ lw, const float* __restrict__ lb,
                               unsigned short* __restrict__ tn) {
  int tok = (blockIdx.x << 2) + (threadIdx.x >> 6);
  int lane = threadIdx.x & 63;
  f32x4 v = *(const f32x4*)(T + ((size_t)tok << 8) + (lane << 2));
  float s = v[0] + v[1] + v[2] + v[3];
  float s2 = v[0] * v[0] + v[1] * v[1] + v[2] * v[2] + v[3] * v[3];
#pragma unroll
  for (int off = 32; off > 0; off >>= 1) {
    s += __shfl_xor(s, off);
    s2 += __shfl_xor(s2, off);
  }
  float mean = s * (1.f / 256.f);
  float rstd = rsqrtf(s2 * (1.f / 256.f) - mean * mean + 1e-5f);
  f32x4 wv = *(const f32x4*)(lw + (lane << 2));
  f32x4 bv = *(const f32x4*)(lb + (lane << 2));
  u16x4 o;
#pragma unroll
  for (int j = 0; j < 4; ++j) o[j] = f2b((v[j] - mean) * rstd * wv[j] + bv[j]);
  *(u16x4*)(tn + ((size_t)tok << 8) + (lane << 2)) = o;
}

// ---------- launch ----------
extern "C" void kernel_launch(void* const* d_in, const int* in_sizes, int n_in,
                              void* d_out, int out_size, void* d_ws, size_t ws_size,
                              hipStream_t stream) {
  const float* x    = (const float*)d_in[0];
  const float* ln1w = (const float*)d_in[1];
  const float* ln1b = (const float*)d_in[2];
  const float* qkvw = (const float*)d_in[3];
  const float* qkvb = (const float*)d_in[4];
  const float* relb = (const float*)d_in[5];
  const float* projw = (const float*)d_in[6];
  const float* projb = (const float*)d_in[7];
  const float* ln2w = (const float*)d_in[8];
  const float* ln2b = (const float*)d_in[9];
  const float* fc1w = (const float*)d_in[10];
  const float* fc1b = (const float*)d_in[11];
  const float* fc2w = (const float*)d_in[12];
  const float* fc2b = (const float*)d_in[13];

  char* ws = (char*)d_ws;
  unsigned short* win = (unsigned short*)(ws);                  // 67,108,864 B
  unsigned short* qkv = (unsigned short*)(ws + 67108864);       // 201,326,592 B
  float* T            = (float*)(ws + 268435456);               // 134,217,728 B
  float* stats1       = (float*)(ws + 402653184);               // 1,048,576 B
  unsigned short* wq  = (unsigned short*)(ws + 404750336);      // 393,216 B
  unsigned short* wp  = (unsigned short*)(ws + 405143552);      // 131,072 B
  unsigned short* w1  = (unsigned short*)(ws + 405274624);      // 524,288 B
  unsigned short* w2  = (unsigned short*)(ws + 405798912);      // 524,288 B -> end 406,323,200
  unsigned short* attn_out = win;                // reuse (win dead after QKV)
  unsigned short* h2  = (unsigned short*)(ws);   // 268 MB (win+qkv regions, dead after proj)
  unsigned short* tn  = (unsigned short*)d_out;  // 67 MB scratch inside d_out (overwritten by FC2)

  if (ws_size < 406323200ull) return;  // workspace too small: fail loudly (poison stays)

  swin_cvt<<<(196608 + 255) / 256, 256, 0, stream>>>(qkvw, wq, 196608);
  swin_cvt<<<(65536 + 255) / 256, 256, 0, stream>>>(projw, wp, 65536);
  swin_cvt<<<(262144 + 255) / 256, 256, 0, stream>>>(fc1w, w1, 262144);
  swin_cvt<<<(262144 + 255) / 256, 256, 0, stream>>>(fc2w, w2, 262144);

  swin_ln1_stats<<<1024, 256, 0, stream>>>(x, stats1);
  swin_win_pass<<<4096, 256, 0, stream>>>(x, stats1, ln1w, ln1b, win);
  swin_gemm<0><<<6144, 256, 0, stream>>>(win, wq, qkvb, qkv, nullptr, 131072, 768, 256);
  swin_attn<<<4096, 256, 0, stream>>>(qkv, relb, attn_out);
  swin_gemm<1><<<2048, 256, 0, stream>>>(attn_out, wp, projb, T, x, 131072, 256, 256);
  swin_ln2_fused<<<32768, 256, 0, stream>>>(T, ln2w, ln2b, tn);
  swin_gemm<2><<<8192, 256, 0, stream>>>(tn, w1, fc1b, h2, nullptr, 131072, 1024, 256);
  swin_gemm<3><<<2048, 256, 0, stream>>>(h2, w2, fc2b, d_out, T, 131072, 256, 1024);
}

// Round 3
// 785.183 us; speedup vs baseline: 1.8764x; 1.0718x over previous
//
#include <hip/hip_runtime.h>
#include <cstdint>
#include <cstddef>

// ---------- types / helpers ----------
using f32x4 = __attribute__((ext_vector_type(4))) float;
using bf16x8 = __attribute__((ext_vector_type(8))) __bf16;
using u16x4 = __attribute__((ext_vector_type(4))) unsigned short;
using u16x8 = __attribute__((ext_vector_type(8))) unsigned short;

#define DEV __device__ __forceinline__

DEV unsigned short f2b(float f) {
  __bf16 h = (__bf16)f;               // native v_cvt (RNE), 1 inst vs 5
  return __builtin_bit_cast(unsigned short, h);
}
DEV float b2f(unsigned short u) {
  uint32_t w = ((uint32_t)u) << 16;
  return __builtin_bit_cast(float, w);
}

// async global->LDS, 16B per lane. LDS dest must be wave-uniform base + lane*16.
DEV void gload16(const unsigned short* g, unsigned short* l) {
  __builtin_amdgcn_global_load_lds(
      (const __attribute__((address_space(1))) void*)g,
      (__attribute__((address_space(3))) void*)l, 16, 0, 0);
}

// Problem constants
// B=8, C=256, H=W=128, HEADS=8, hd=32, WS=8, SHIFT=4, nW=256, tokens=131072

// ---------- all weight casts fp32 -> bf16, one launch ----------
__global__ void swin_cvt_all(const float* __restrict__ qkvw, const float* __restrict__ projw,
                             const float* __restrict__ fc1w, const float* __restrict__ fc2w,
                             unsigned short* __restrict__ wq, unsigned short* __restrict__ wp,
                             unsigned short* __restrict__ w1, unsigned short* __restrict__ w2) {
  int i = blockIdx.x * 256 + threadIdx.x;           // 0 .. 786431
  if (i < 196608) wq[i] = f2b(qkvw[i]);
  else if (i < 262144) wp[i - 196608] = f2b(projw[i - 196608]);
  else if (i < 524288) w1[i - 262144] = f2b(fc1w[i - 262144]);
  else w2[i - 524288] = f2b(fc2w[i - 524288]);
}

// ---------- LN1 stats over channel dim, reading x in (B,C,H,W) coalesced ----------
__global__ void swin_ln1_stats(const float* __restrict__ x, float* __restrict__ st) {
  __shared__ float sh[512];
  int bh = blockIdx.x;          // b*128 + h
  int t = threadIdx.x;
  int w = t & 127, ch = t >> 7; // channel-half
  const float* px = x + (((size_t)(bh >> 7) * 256 + ch * 128) << 14) + ((size_t)(bh & 127) << 7) + w;
  float s = 0.f, s2 = 0.f;
  for (int c = 0; c < 128; ++c) {
    float v = px[(size_t)c << 14];
    s += v; s2 += v * v;
  }
  sh[t] = s; sh[256 + t] = s2;
  __syncthreads();
  if (ch == 0) {
    s += sh[t + 128]; s2 += sh[256 + t + 128];
    float mean = s * (1.f / 256.f);
    float var = s2 * (1.f / 256.f) - mean * mean;
    int tok = (bh << 7) + w;
    st[(size_t)tok * 2] = mean;
    st[(size_t)tok * 2 + 1] = rsqrtf(var + 1e-5f);
  }
}

// ---------- normalize + cyclic shift + window partition -> win bf16 (2048,64,256) ----------
__global__ void swin_win_pass(const float* __restrict__ x, const float* __restrict__ st,
                              const float* __restrict__ lw, const float* __restrict__ lb,
                              unsigned short* __restrict__ win) {
  __shared__ float tile[64 * 129];
  int bid = blockIdx.x;
  int ct = bid & 3; int bh = bid >> 2;
  int b = bh >> 7, h = bh & 127;
  int c0 = ct << 6;
  int t = threadIdx.x;
#pragma unroll
  for (int i = 0; i < 32; ++i) {
    int id = (i << 8) + t;
    int cl_ = id >> 7, w = id & 127;
    tile[cl_ * 129 + w] = x[(((size_t)(b * 256 + c0 + cl_)) << 14) + (h << 7) + w];
  }
  __syncthreads();
  int hp = (h + 124) & 127;           // shifted row coord
  int whh = hp >> 3, nh = hp & 7;
#pragma unroll
  for (int i = 0; i < 32; ++i) {
    int id = (i << 8) + t;
    int w = id >> 6, cc = id & 63;
    float mean = st[(((size_t)bh << 7) + w) * 2];
    float rstd = st[(((size_t)bh << 7) + w) * 2 + 1];
    float v = tile[cc * 129 + w];
    v = (v - mean) * rstd * lw[c0 + cc] + lb[c0 + cc];
    int wp_ = (w + 124) & 127;        // shifted col coord
    int wwc = wp_ >> 3, nw = wp_ & 7;
    size_t wt = (size_t)b * 256 + whh * 16 + wwc;
    int n = (nh << 3) + nw;
    win[((wt << 6) + n) * 256 + c0 + cc] = f2b(v);
  }
}

// ---------- bf16 GEMM: C = A(M,K) @ W(N,K)^T, double-buffered global_load_lds ----------
// LDS linear [128][32] u16; 16B chunk kc within row holds global chunk kc^((row>>1)&3)
// (row stride = 64B = 16 banks, so xor must span 8 bank-groups -> use bit1..2 of row).
// MODE 0: QKV  -> bf16 out (ld 768), bias, scale q-part       [swapped: 4 cols/lane reg]
// MODE 1: PROJ -> bf16 T token-major, bias + x shortcut       [swapped]
// MODE 2: FC1  -> bf16 h2 (ld 1024), bias + gelu              [swapped]
// MODE 3: FC2  -> fp32 d_out NCHW, bias + T(bf16) residual    [unswapped: 4 rows/lane reg]
template<int MODE>
__global__ __launch_bounds__(256)
void swin_gemm(const unsigned short* __restrict__ A,
               const unsigned short* __restrict__ Wt,
               const float* __restrict__ bias,
               void* __restrict__ outp,
               const void* __restrict__ extra,
               int M, int N, int K) {
  __shared__ unsigned short As[2][128 * 32];
  __shared__ unsigned short Bs[2][128 * 32];
  // XCD-chunked swizzle (grid % 8 == 0): XCD k gets contiguous tile chunk.
  const int cpx = gridDim.x >> 3;
  const int bid = (blockIdx.x & 7) * cpx + (blockIdx.x >> 3);
  const int nbn = N >> 7;
  const int bm = bid / nbn;
  const int bn = bid % nbn;
  const int m0 = bm << 7, n0 = bn << 7;
  const int t = threadIdx.x;
  const int lane = t & 63;
  const int wave = t >> 6;
  const int wr = wave >> 1, wc = wave & 1;
  const int cl = lane & 15, g = lane >> 4;
  const int KT = K >> 5;

  // staging: chunk id t -> row=(t>>2), kc=t&3; source k-chunk = kc^((row>>1)&3)
  const int row0 = t >> 2;            // 0..63
  const int ks = (t & 3) ^ ((row0 >> 1) & 3);
  const size_t aoff0 = (size_t)(m0 + row0) * K + ks * 8;
  const size_t aoff1 = (size_t)(m0 + 64 + row0) * K + ks * 8;
  const size_t boff0 = (size_t)(n0 + row0) * K + ks * 8;
  const size_t boff1 = (size_t)(n0 + 64 + row0) * K + ks * 8;

  // fragment read: row r_ = base+cl; (r_>>1)&3 == (cl>>1)&3 (bases are mult. of 16)
  const int ra_ = wr * 64 + cl;
  const int rb_ = wc * 64 + cl;
  const int ka = (g ^ ((cl >> 1) & 3)) * 8;

  auto stage = [&](int buf, int kt) {
    const size_t ko = (size_t)kt * 32;
    unsigned short* la = As[buf] + t * 8;
    unsigned short* lb = Bs[buf] + t * 8;
    gload16(A + aoff0 + ko, la);
    gload16(A + aoff1 + ko, la + 2048);
    gload16(Wt + boff0 + ko, lb);
    gload16(Wt + boff1 + ko, lb + 2048);
  };

  f32x4 acc[4][4] = {};

  stage(0, 0);
  __syncthreads();
  int cur = 0;
  for (int kt = 0; kt < KT; ++kt) {
    if (kt + 1 < KT) stage(cur ^ 1, kt + 1);   // overlap next-tile loads with compute
    bf16x8 af[4], bfr[4];
#pragma unroll
    for (int i = 0; i < 4; ++i) {
      af[i]  = *(const bf16x8*)&As[cur][(ra_ + i * 16) * 32 + ka];
      bfr[i] = *(const bf16x8*)&Bs[cur][(rb_ + i * 16) * 32 + ka];
    }
#pragma unroll
    for (int i = 0; i < 4; ++i)
#pragma unroll
      for (int j = 0; j < 4; ++j) {
        if constexpr (MODE == 3)
          acc[i][j] = __builtin_amdgcn_mfma_f32_16x16x32_bf16(af[i], bfr[j], acc[i][j], 0, 0, 0);
        else
          acc[i][j] = __builtin_amdgcn_mfma_f32_16x16x32_bf16(bfr[j], af[i], acc[i][j], 0, 0, 0);
      }
    __syncthreads();                            // single vmcnt(0)+barrier per K-step
    cur ^= 1;
  }

  if constexpr (MODE == 3) {
    const unsigned short* Tb = (const unsigned short*)extra;
#pragma unroll
    for (int i = 0; i < 4; ++i) {
      int rowb = m0 + wr * 64 + i * 16 + (g << 2);
      int b = rowb >> 14, hw = rowb & 16383;
#pragma unroll
      for (int j = 0; j < 4; ++j) {
        int col = n0 + wc * 64 + j * 16 + cl;
        float bs = bias[col];
        f32x4 vv;
#pragma unroll
        for (int r = 0; r < 4; ++r)
          vv[r] = acc[i][j][r] + bs + b2f(Tb[((size_t)(rowb + r) << 8) + col]);
        *(f32x4*)&((float*)outp)[(((size_t)(b << 8) + col) << 14) + hw] = vv;
      }
    }
  } else {
    const float* xf = (const float*)extra;
#pragma unroll
    for (int i = 0; i < 4; ++i) {
      int row = m0 + wr * 64 + i * 16 + cl;
#pragma unroll
      for (int j = 0; j < 4; ++j) {
        int colb = n0 + wc * 64 + j * 16 + (g << 2);
        f32x4 b4 = *(const f32x4*)(bias + colb);
        if constexpr (MODE == 0) {
          const bool qs = (n0 < 256);
          u16x4 o;
#pragma unroll
          for (int r = 0; r < 4; ++r) {
            float v = acc[i][j][r] + b4[r];
            if (qs) v *= 0.17677669529663687f;  // 1/sqrt(32)
            o[r] = f2b(v);
          }
          *(u16x4*)((unsigned short*)outp + (size_t)row * 768 + colb) = o;
        } else if constexpr (MODE == 1) {
          int b = row >> 14, hw = row & 16383;
          u16x4 o;
#pragma unroll
          for (int r = 0; r < 4; ++r)
            o[r] = f2b(acc[i][j][r] + b4[r] +
                       xf[((size_t)(b * 256 + colb + r) << 14) + hw]);
          *(u16x4*)((unsigned short*)outp + (size_t)row * 256 + colb) = o;
        } else {  // MODE 2: FC1 + gelu(tanh)
          u16x4 o;
#pragma unroll
          for (int r = 0; r < 4; ++r) {
            float v = acc[i][j][r] + b4[r];
            float u = 0.7978845608028654f * (v + 0.044715f * v * v * v);
            float e = __expf(2.f * u);
            o[r] = f2b(v * e / (e + 1.f));      // v*sigmoid(2u) == 0.5v(1+tanh(u))
          }
          *(u16x4*)((unsigned short*)outp + (size_t)row * 1024 + colb) = o;
        }
      }
    }
  }
}

// ---------- windowed attention: one block = (window, 4 heads), 1 wave/head ----------
// Output written in TOKEN order (window-reverse + unshift fused into the store).
__global__ __launch_bounds__(256)
void swin_attn(const unsigned short* __restrict__ qkv,
               const float* __restrict__ relb,
               unsigned short* __restrict__ attn_out) {
  __shared__ unsigned short Plds[4][64 * 68];
  __shared__ unsigned short Vlds[4][32 * 68];
  int bid = blockIdx.x;
  int w = bid >> 1, hg = bid & 1;
  int t = threadIdx.x;
  int wave = t >> 6, lane = t & 63;
  int head = (hg << 2) + wave;
  int cl = lane & 15, g = lane >> 4;
  const size_t wb = (size_t)w * 64 * 768;

  bf16x8 qf[4], kf[4];
#pragma unroll
  for (int ni = 0; ni < 4; ++ni) {
    int n = (ni << 4) + cl;
    qf[ni] = *(const bf16x8*)(qkv + wb + (size_t)n * 768 + (head << 5) + (g << 3));
    kf[ni] = *(const bf16x8*)(qkv + wb + (size_t)n * 768 + 256 + (head << 5) + (g << 3));
  }

  f32x4 s[4][4] = {};
#pragma unroll
  for (int mi = 0; mi < 4; ++mi)
#pragma unroll
    for (int ni = 0; ni < 4; ++ni)
      s[mi][ni] = __builtin_amdgcn_mfma_f32_16x16x32_bf16(kf[mi], qf[ni], s[mi][ni], 0, 0, 0);

#pragma unroll
  for (int c = 0; c < 4; ++c) {
    int id = (c << 6) + lane;
    int m = id >> 2, dc = (id & 3) << 3;
    u16x8 vv = *(const u16x8*)(qkv + wb + (size_t)m * 768 + 512 + (head << 5) + dc);
#pragma unroll
    for (int j = 0; j < 8; ++j)
      Vlds[wave][(dc + j) * 68 + m] = vv[j];
  }

  int wi = w & 255;
  bool eh = (wi >> 4) == 15, ew = (wi & 15) == 15;
#pragma unroll
  for (int ni = 0; ni < 4; ++ni) {
    int n = (ni << 4) + cl;
    int nh = n >> 3, nw = n & 7;
    int rn = (eh ? ((nh >> 2) + 1) : 0) * 3 + (ew ? ((nw >> 2) + 1) : 0);
    float mx = -1e30f;
#pragma unroll
    for (int mi = 0; mi < 4; ++mi)
#pragma unroll
      for (int r = 0; r < 4; ++r) {
        int m = (mi << 4) + (g << 2) + r;
        int mh = m >> 3, mw = m & 7;
        int rm = (eh ? ((mh >> 2) + 1) : 0) * 3 + (ew ? ((mw >> 2) + 1) : 0);
        float v = s[mi][ni][r] + relb[(size_t)((nh - mh + 7) * 15 + (nw - mw + 7)) * 8 + head];
        if (rn != rm) v -= 100.f;
        s[mi][ni][r] = v;
        mx = fmaxf(mx, v);
      }
    mx = fmaxf(mx, __shfl_xor(mx, 16));
    mx = fmaxf(mx, __shfl_xor(mx, 32));
    float sum = 0.f;
#pragma unroll
    for (int mi = 0; mi < 4; ++mi)
#pragma unroll
      for (int r = 0; r < 4; ++r) {
        float p = __expf(s[mi][ni][r] - mx);
        s[mi][ni][r] = p;
        sum += p;
      }
    sum += __shfl_xor(sum, 16);
    sum += __shfl_xor(sum, 32);
    float inv = 1.f / sum;
#pragma unroll
    for (int mi = 0; mi < 4; ++mi) {
      u16x4 pk;
#pragma unroll
      for (int r = 0; r < 4; ++r) pk[r] = f2b(s[mi][ni][r] * inv);
      *(u16x4*)&Plds[wave][n * 68 + (mi << 4) + (g << 2)] = pk;
    }
  }
  __syncthreads();

  union FragU { bf16x8 v; uint64_t q[2]; };
  f32x4 o[4][2] = {};
#pragma unroll
  for (int mt = 0; mt < 2; ++mt) {
    FragU vf[2];
#pragma unroll
    for (int dt = 0; dt < 2; ++dt) {
      int d = (dt << 4) + cl;
      const unsigned short* p = &Vlds[wave][d * 68 + (mt << 5) + (g << 3)];
      vf[dt].q[0] = *(const uint64_t*)p;
      vf[dt].q[1] = *(const uint64_t*)(p + 4);
    }
#pragma unroll
    for (int ni = 0; ni < 4; ++ni) {
      FragU pa;
      const unsigned short* pp = &Plds[wave][((ni << 4) + cl) * 68 + (mt << 5) + (g << 3)];
      pa.q[0] = *(const uint64_t*)pp;
      pa.q[1] = *(const uint64_t*)(pp + 4);
#pragma unroll
      for (int dt = 0; dt < 2; ++dt)
        o[ni][dt] = __builtin_amdgcn_mfma_f32_16x16x32_bf16(pa.v, vf[dt].v, o[ni][dt], 0, 0, 0);
    }
  }

  int b = w >> 8;
#pragma unroll
  for (int ni = 0; ni < 4; ++ni)
#pragma unroll
    for (int dt = 0; dt < 2; ++dt)
#pragma unroll
      for (int r = 0; r < 4; ++r) {
        int n = (ni << 4) + (g << 2) + r;
        int d = (dt << 4) + cl;
        int hs = ((wi >> 4) << 3) + (n >> 3), ws_ = ((wi & 15) << 3) + (n & 7);
        int hh = (hs + 4) & 127, ww = (ws_ + 4) & 127;
        size_t tok = ((size_t)b << 14) + (hh << 7) + ww;
        attn_out[tok * 256 + (head << 5) + d] = f2b(o[ni][dt][r]);
      }
}

// ---------- fused LN2: stats + normalize, T bf16 in -> tn bf16 out ----------
__global__ void swin_ln2_fused(const unsigned short* __restrict__ Tb,
                               const float* __restrict__ lw, const float* __restrict__ lb,
                               unsigned short* __restrict__ tn) {
  int tok = (blockIdx.x << 2) + (threadIdx.x >> 6);
  int lane = threadIdx.x & 63;
  u16x4 tv = *(const u16x4*)(Tb + ((size_t)tok << 8) + (lane << 2));
  f32x4 v;
#pragma unroll
  for (int j = 0; j < 4; ++j) v[j] = b2f(tv[j]);
  float s = v[0] + v[1] + v[2] + v[3];
  float s2 = v[0] * v[0] + v[1] * v[1] + v[2] * v[2] + v[3] * v[3];
#pragma unroll
  for (int off = 32; off > 0; off >>= 1) {
    s += __shfl_xor(s, off);
    s2 += __shfl_xor(s2, off);
  }
  float mean = s * (1.f / 256.f);
  float rstd = rsqrtf(s2 * (1.f / 256.f) - mean * mean + 1e-5f);
  f32x4 wv = *(const f32x4*)(lw + (lane << 2));
  f32x4 bv = *(const f32x4*)(lb + (lane << 2));
  u16x4 o;
#pragma unroll
  for (int j = 0; j < 4; ++j) o[j] = f2b((v[j] - mean) * rstd * wv[j] + bv[j]);
  *(u16x4*)(tn + ((size_t)tok << 8) + (lane << 2)) = o;
}

// ---------- launch ----------
extern "C" void kernel_launch(void* const* d_in, const int* in_sizes, int n_in,
                              void* d_out, int out_size, void* d_ws, size_t ws_size,
                              hipStream_t stream) {
  const float* x    = (const float*)d_in[0];
  const float* ln1w = (const float*)d_in[1];
  const float* ln1b = (const float*)d_in[2];
  const float* qkvw = (const float*)d_in[3];
  const float* qkvb = (const float*)d_in[4];
  const float* relb = (const float*)d_in[5];
  const float* projw = (const float*)d_in[6];
  const float* projb = (const float*)d_in[7];
  const float* ln2w = (const float*)d_in[8];
  const float* ln2b = (const float*)d_in[9];
  const float* fc1w = (const float*)d_in[10];
  const float* fc1b = (const float*)d_in[11];
  const float* fc2w = (const float*)d_in[12];
  const float* fc2b = (const float*)d_in[13];

  char* ws = (char*)d_ws;
  unsigned short* win = (unsigned short*)(ws);                  // 67,108,864 B
  unsigned short* qkv = (unsigned short*)(ws + 67108864);       // 201,326,592 B
  unsigned short* T   = (unsigned short*)(ws + 268435456);      // 67,108,864 B (bf16 now)
  float* stats1       = (float*)(ws + 402653184);               // 1,048,576 B
  unsigned short* wq  = (unsigned short*)(ws + 404750336);      // 393,216 B
  unsigned short* wp  = (unsigned short*)(ws + 405143552);      // 131,072 B
  unsigned short* w1  = (unsigned short*)(ws + 405274624);      // 524,288 B
  unsigned short* w2  = (unsigned short*)(ws + 405798912);      // 524,288 B -> end 406,323,200
  unsigned short* attn_out = win;                // reuse (win dead after QKV)
  unsigned short* h2  = (unsigned short*)(ws);   // 268 MB (win+qkv regions, dead after proj)
  unsigned short* tn  = (unsigned short*)d_out;  // 67 MB scratch inside d_out (overwritten by FC2)

  if (ws_size < 406323200ull) return;  // workspace too small: fail loudly (poison stays)

  swin_cvt_all<<<3072, 256, 0, stream>>>(qkvw, projw, fc1w, fc2w, wq, wp, w1, w2);
  swin_ln1_stats<<<1024, 256, 0, stream>>>(x, stats1);
  swin_win_pass<<<4096, 256, 0, stream>>>(x, stats1, ln1w, ln1b, win);
  swin_gemm<0><<<6144, 256, 0, stream>>>(win, wq, qkvb, qkv, nullptr, 131072, 768, 256);
  swin_attn<<<4096, 256, 0, stream>>>(qkv, relb, attn_out);
  swin_gemm<1><<<2048, 256, 0, stream>>>(attn_out, wp, projb, T, x, 131072, 256, 256);
  swin_ln2_fused<<<32768, 256, 0, stream>>>(T, ln2w, ln2b, tn);
  swin_gemm<2><<<8192, 256, 0, stream>>>(tn, w1, fc1b, h2, nullptr, 131072, 1024, 256);
  swin_gemm<3><<<2048, 256, 0, stream>>>(h2, w2, fc2b, d_out, T, 131072, 256, 1024);
}